// Round 1
// baseline (650.560 us; speedup 1.0000x reference)
//
#include <hip/hip_runtime.h>

// ---------------------------------------------------------------------------
// Attention (GQA + RoPE + softcap + causal) on gfx950, bf16 MFMA pipeline.
// B=2 T=2048 D=2048, NH=16 NKV=8 HD=128, softcap=50, causal.
// Stages: cvt x -> bf16 | transpose w_q/w_kv/w_out -> B^T bf16 | QKV GEMM |
//         RoPE(+scale q) | V transpose | flash attention | out GEMM (fp32).
// ---------------------------------------------------------------------------

#define LOG2E 1.4426950408889634f

typedef unsigned short u16;
typedef __attribute__((ext_vector_type(8))) short short8;   // 8 x bf16 (4 VGPRs)
typedef __attribute__((ext_vector_type(4))) float floatx4;  // MFMA acc

static __device__ __forceinline__ u16 f2b(float f){
  unsigned u = __float_as_uint(f);
  u = (u + 0x7fffu + ((u >> 16) & 1u)) >> 16;   // RNE
  return (u16)u;
}
static __device__ __forceinline__ float b2f(u16 u){
  return __uint_as_float(((unsigned)u) << 16);
}

// ---- x fp32 -> bf16 (vectorized) ------------------------------------------
__global__ void k_cvt_x(const float* __restrict__ x, u16* __restrict__ xb){
  int i = blockIdx.x * 256 + threadIdx.x;     // exactly 2,097,152 threads
  float4 v = ((const float4*)x)[i];
  ushort4 o = make_ushort4(f2b(v.x), f2b(v.y), f2b(v.z), f2b(v.w));
  ((ushort4*)xb)[i] = o;
}

// ---- generic fp32 -> bf16 transpose (64x64 LDS tiles) ---------------------
// src matrix z: [R rows x C cols], row stride sRS; dst: [C x R], row stride dRS.
__global__ void k_tr_f32(const float* __restrict__ src, u16* __restrict__ dst,
                         int sRS, int dRS, long sMS, long dMS){
  __shared__ float t[64][65];
  const float* s = src + (long)blockIdx.z * sMS + (long)blockIdx.y * 64 * sRS + (long)blockIdx.x * 64;
  u16* d = dst + (long)blockIdx.z * dMS + (long)blockIdx.x * 64 * dRS + (long)blockIdx.y * 64;
  int tid = threadIdx.x;
  #pragma unroll
  for(int i = 0; i < 16; i++){
    int idx = tid + 256 * i;
    t[idx >> 6][idx & 63] = s[(long)(idx >> 6) * sRS + (idx & 63)];
  }
  __syncthreads();
  #pragma unroll
  for(int i = 0; i < 16; i++){
    int idx = tid + 256 * i;
    d[(long)(idx >> 6) * dRS + (idx & 63)] = f2b(t[idx & 63][idx >> 6]);
  }
}

// ---- v transpose: v_buf[4096][1024] -> v_t[2][8][128][2048] ----------------
__global__ void k_tr_v(const u16* __restrict__ src, u16* __restrict__ dst){
  __shared__ u16 t[64][65];
  int z = blockIdx.z;                           // b*8 + kv
  const u16* s = src + ((long)(z >> 3) * 2048 + (long)blockIdx.y * 64) * 1024
                     + (z & 7) * 128 + blockIdx.x * 64;
  u16* d = dst + (long)z * 262144 + (long)blockIdx.x * 64 * 2048 + blockIdx.y * 64;
  int tid = threadIdx.x;
  #pragma unroll
  for(int i = 0; i < 16; i++){
    int idx = tid + 256 * i;
    t[idx >> 6][idx & 63] = s[(long)(idx >> 6) * 1024 + (idx & 63)];
  }
  __syncthreads();
  #pragma unroll
  for(int i = 0; i < 16; i++){
    int idx = tid + 256 * i;
    d[(long)(idx >> 6) * 2048 + (idx & 63)] = t[idx & 63][idx >> 6];
  }
}

// ---- fused QKV projection GEMM --------------------------------------------
// A = x_bf16 [4096 x 2048]; B^T tiles from wq_t/wkv_t (row stride 2048).
// nt<16 -> q head nt ; 16..23 -> k head nt-16 ; 24..31 -> v head nt-24.
__global__ __launch_bounds__(256) void k_gemm_qkv(
    const u16* __restrict__ A, const u16* __restrict__ wq_t, const u16* __restrict__ wkv_t,
    u16* __restrict__ qb, u16* __restrict__ kb, u16* __restrict__ vb){
  __shared__ __attribute__((aligned(16))) u16 sA[128][72];  // +8 pad: b128 reads at bank floor
  __shared__ __attribute__((aligned(16))) u16 sB[128][72];
  int mt = blockIdx.x, nt = blockIdx.y;
  const u16* Bt; u16* dst; int dS, dcol;
  if(nt < 16){ Bt = wq_t + (long)nt * 262144; dst = qb; dS = 2048; dcol = nt * 128; }
  else {
    Bt = wkv_t + (long)(nt - 16) * 262144;            // k heads 0..7, v heads 8..15
    dS = 1024;
    if(nt < 24){ dst = kb; dcol = (nt - 16) * 128; }
    else       { dst = vb; dcol = (nt - 24) * 128; }
  }
  int tid = threadIdx.x;
  int lane = tid & 63, wave = tid >> 6, l15 = lane & 15, quad = lane >> 4;
  int ro = (wave & 1) * 64, co = (wave >> 1) * 64;
  int arow = tid >> 3, akc = tid & 7;                  // staging: 16B chunks
  const u16* Ag = A + ((long)mt * 128 + arow) * 2048 + akc * 8;
  const u16* Bg = Bt + (long)arow * 2048 + akc * 8;
  floatx4 acc[4][4];
  const floatx4 fz = {0.f, 0.f, 0.f, 0.f};
  #pragma unroll
  for(int r = 0; r < 4; r++)
    #pragma unroll
    for(int c = 0; c < 4; c++) acc[r][c] = fz;
  for(int k0 = 0; k0 < 2048; k0 += 64){
    #pragma unroll
    for(int i = 0; i < 4; i++){
      uint4 va  = *(const uint4*)(Ag + (long)(32 * i) * 2048 + k0);
      uint4 vb4 = *(const uint4*)(Bg + (long)(32 * i) * 2048 + k0);
      *(uint4*)&sA[arow + 32 * i][akc * 8] = va;
      *(uint4*)&sB[arow + 32 * i][akc * 8] = vb4;
    }
    __syncthreads();
    #pragma unroll
    for(int ks = 0; ks < 2; ks++){
      short8 af[4], bfr[4];
      #pragma unroll
      for(int r = 0; r < 4; r++) af[r]  = *(const short8*)&sA[ro + r * 16 + l15][ks * 32 + quad * 8];
      #pragma unroll
      for(int c = 0; c < 4; c++) bfr[c] = *(const short8*)&sB[co + c * 16 + l15][ks * 32 + quad * 8];
      #pragma unroll
      for(int r = 0; r < 4; r++)
        #pragma unroll
        for(int c = 0; c < 4; c++)
          acc[r][c] = __builtin_amdgcn_mfma_f32_16x16x32_bf16(af[r], bfr[c], acc[r][c], 0, 0, 0);
    }
    __syncthreads();
  }
  long rb0 = (long)mt * 128 + ro + quad * 4;           // C layout: row=quad*4+reg, col=l15
  #pragma unroll
  for(int r = 0; r < 4; r++)
    #pragma unroll
    for(int c = 0; c < 4; c++){
      int col = dcol + co + c * 16 + l15;
      #pragma unroll
      for(int j = 0; j < 4; j++)
        dst[(rb0 + r * 16 + j) * dS + col] = f2b(acc[r][c][j]);
    }
}

// ---- out projection GEMM: enc[4096x2048] x w_out -> fp32 out ---------------
__global__ __launch_bounds__(256) void k_gemm_out(
    const u16* __restrict__ A, const u16* __restrict__ Bt0, float* __restrict__ C){
  __shared__ __attribute__((aligned(16))) u16 sA[128][72];
  __shared__ __attribute__((aligned(16))) u16 sB[128][72];
  int mt = blockIdx.x, nt = blockIdx.y;
  const u16* Bt = Bt0 + (long)nt * 262144;
  int tid = threadIdx.x;
  int lane = tid & 63, wave = tid >> 6, l15 = lane & 15, quad = lane >> 4;
  int ro = (wave & 1) * 64, co = (wave >> 1) * 64;
  int arow = tid >> 3, akc = tid & 7;
  const u16* Ag = A + ((long)mt * 128 + arow) * 2048 + akc * 8;
  const u16* Bg = Bt + (long)arow * 2048 + akc * 8;
  floatx4 acc[4][4];
  const floatx4 fz = {0.f, 0.f, 0.f, 0.f};
  #pragma unroll
  for(int r = 0; r < 4; r++)
    #pragma unroll
    for(int c = 0; c < 4; c++) acc[r][c] = fz;
  for(int k0 = 0; k0 < 2048; k0 += 64){
    #pragma unroll
    for(int i = 0; i < 4; i++){
      uint4 va  = *(const uint4*)(Ag + (long)(32 * i) * 2048 + k0);
      uint4 vb4 = *(const uint4*)(Bg + (long)(32 * i) * 2048 + k0);
      *(uint4*)&sA[arow + 32 * i][akc * 8] = va;
      *(uint4*)&sB[arow + 32 * i][akc * 8] = vb4;
    }
    __syncthreads();
    #pragma unroll
    for(int ks = 0; ks < 2; ks++){
      short8 af[4], bfr[4];
      #pragma unroll
      for(int r = 0; r < 4; r++) af[r]  = *(const short8*)&sA[ro + r * 16 + l15][ks * 32 + quad * 8];
      #pragma unroll
      for(int c = 0; c < 4; c++) bfr[c] = *(const short8*)&sB[co + c * 16 + l15][ks * 32 + quad * 8];
      #pragma unroll
      for(int r = 0; r < 4; r++)
        #pragma unroll
        for(int c = 0; c < 4; c++)
          acc[r][c] = __builtin_amdgcn_mfma_f32_16x16x32_bf16(af[r], bfr[c], acc[r][c], 0, 0, 0);
    }
    __syncthreads();
  }
  long rb0 = (long)mt * 128 + ro + quad * 4;
  #pragma unroll
  for(int r = 0; r < 4; r++)
    #pragma unroll
    for(int c = 0; c < 4; c++){
      int col = nt * 128 + co + c * 16 + l15;
      #pragma unroll
      for(int j = 0; j < 4; j++)
        C[(rb0 + r * 16 + j) * 2048 + col] = acc[r][c][j];
    }
}

// ---- RoPE (q: rope + 1/sqrt(128); k: rope) in-place on bf16 ----------------
__global__ void k_rope(u16* __restrict__ qb, u16* __restrict__ kb, const int* __restrict__ pos){
  int idx = blockIdx.x * 256 + threadIdx.x;    // exactly 6,291,456 threads
  const int NQ = 4096 * 16 * 64;
  u16* p1; int row, h; float scale;
  if(idx < NQ){
    row = idx >> 10;
    int rr = idx & 1023;
    int n = rr >> 6; h = rr & 63;
    p1 = qb + (long)row * 2048 + n * 128 + h;
    scale = 0.08838834764831845f;              // HEAD_DIM^-0.5
  } else {
    int j = idx - NQ;
    row = j >> 9;
    int rr = j & 511;
    int n = rr >> 6; h = rr & 63;
    p1 = kb + (long)row * 1024 + n * 128 + h;
    scale = 1.0f;
  }
  float pf = (float)pos[row];
  float inv = exp2f(-0.20762050593045077f * (float)h);  // 10000^(-h/64)
  float ang = pf * inv;
  float sv = sinf(ang), cv = cosf(ang);
  float x1 = b2f(p1[0]), x2 = b2f(p1[64]);
  float o1 = (x1 * cv - x2 * sv) * scale;
  float o2 = (x2 * cv + x1 * sv) * scale;
  p1[0] = f2b(o1); p1[64] = f2b(o2);
}

// ---- flash attention: Q-tile 64 (4 waves x 16 rows), K-tile 64, causal -----
__global__ __launch_bounds__(256) void k_flash(
    const u16* __restrict__ qb, const u16* __restrict__ kb,
    const u16* __restrict__ vt, u16* __restrict__ enc){
  __shared__ __attribute__((aligned(16))) u16 sQ[64][136];
  __shared__ __attribute__((aligned(16))) u16 sK[64][136];
  __shared__ __attribute__((aligned(16))) u16 sVt[128][72];
  __shared__ __attribute__((aligned(16))) u16 sP[4][16][72];
  int qt = blockIdx.x, hidx = blockIdx.y;
  int b = hidx >> 4, kv = (hidx >> 1) & 7, g = hidx & 1;
  int tid = threadIdx.x;
  int lane = tid & 63, wave = tid >> 6, l15 = lane & 15, quad = lane >> 4;
  {                                            // stage Q tile once
    int rr = tid >> 4, hc = tid & 15;
    const u16* qg = qb + ((long)b * 2048 + qt * 64 + rr) * 2048 + (kv * 2 + g) * 128 + hc * 8;
    #pragma unroll
    for(int i = 0; i < 4; i++)
      *(uint4*)&sQ[rr + 16 * i][hc * 8] = *(const uint4*)(qg + (long)(16 * i) * 2048);
  }
  float m_i[4], l_i[4];
  floatx4 o_acc[8];
  const floatx4 fz = {0.f, 0.f, 0.f, 0.f};
  #pragma unroll
  for(int r = 0; r < 4; r++){ m_i[r] = -3.0e38f; l_i[r] = 0.f; }
  #pragma unroll
  for(int c = 0; c < 8; c++) o_acc[c] = fz;
  int rowg0 = qt * 64 + wave * 16 + quad * 4;
  for(int kt = 0; kt <= qt; kt++){
    __syncthreads();
    {                                          // stage K and V^T tiles
      int rr = tid >> 4, hc = tid & 15;
      const u16* kg = kb + ((long)b * 2048 + kt * 64 + rr) * 1024 + kv * 128 + hc * 8;
      #pragma unroll
      for(int i = 0; i < 4; i++)
        *(uint4*)&sK[rr + 16 * i][hc * 8] = *(const uint4*)(kg + (long)(16 * i) * 1024);
      int hr = tid >> 3, sc = tid & 7;
      const u16* vg = vt + ((long)(b * 8 + kv) * 128 + hr) * 2048 + kt * 64 + sc * 8;
      #pragma unroll
      for(int i = 0; i < 4; i++)
        *(uint4*)&sVt[hr + 32 * i][sc * 8] = *(const uint4*)(vg + (long)(32 * i) * 2048);
    }
    __syncthreads();
    floatx4 s_acc[4];
    #pragma unroll
    for(int c = 0; c < 4; c++) s_acc[c] = fz;
    #pragma unroll
    for(int ks = 0; ks < 4; ks++){             // S = Q K^T (K over H=128)
      short8 aq = *(const short8*)&sQ[wave * 16 + l15][ks * 32 + quad * 8];
      #pragma unroll
      for(int cb = 0; cb < 4; cb++){
        short8 bk = *(const short8*)&sK[cb * 16 + l15][ks * 32 + quad * 8];
        s_acc[cb] = __builtin_amdgcn_mfma_f32_16x16x32_bf16(aq, bk, s_acc[cb], 0, 0, 0);
      }
    }
    bool diag = (kt == qt);
    float p[4][4];
    #pragma unroll
    for(int r = 0; r < 4; r++){
      float mx = -3.0e38f;
      #pragma unroll
      for(int cb = 0; cb < 4; cb++){
        float sv = fminf(s_acc[cb][r], 1000.f);
        float t  = exp2f(sv * (2.f * LOG2E / 50.f));     // e^(2s/50)
        float z  = 50.f * (t - 1.f) / (t + 1.f);          // 50*tanh(s/50)
        if(diag && (kt * 64 + cb * 16 + l15 > rowg0 + r)) z = -3.0e38f;
        p[cb][r] = z;
        mx = fmaxf(mx, z);
      }
      #pragma unroll
      for(int off = 1; off < 16; off <<= 1) mx = fmaxf(mx, __shfl_xor(mx, off));
      float mnew  = fmaxf(m_i[r], mx);
      float alpha = exp2f((m_i[r] - mnew) * LOG2E);
      m_i[r] = mnew;
      float rs = 0.f;
      #pragma unroll
      for(int cb = 0; cb < 4; cb++){
        float pe = exp2f((p[cb][r] - mnew) * LOG2E);
        p[cb][r] = pe;
        rs += pe;
      }
      #pragma unroll
      for(int off = 1; off < 16; off <<= 1) rs += __shfl_xor(rs, off);
      l_i[r] = l_i[r] * alpha + rs;
      #pragma unroll
      for(int c = 0; c < 8; c++) o_acc[c][r] *= alpha;
      #pragma unroll
      for(int cb = 0; cb < 4; cb++) sP[wave][quad * 4 + r][cb * 16 + l15] = f2b(p[cb][r]);
    }
    #pragma unroll
    for(int ks2 = 0; ks2 < 2; ks2++){          // O += P V  (K over s=64)
      short8 ap = *(const short8*)&sP[wave][l15][ks2 * 32 + quad * 8];
      #pragma unroll
      for(int c = 0; c < 8; c++){
        short8 bv = *(const short8*)&sVt[c * 16 + l15][ks2 * 32 + quad * 8];
        o_acc[c] = __builtin_amdgcn_mfma_f32_16x16x32_bf16(ap, bv, o_acc[c], 0, 0, 0);
      }
    }
  }
  #pragma unroll
  for(int r = 0; r < 4; r++){
    float invl = 1.f / l_i[r];
    long rowe = (long)b * 2048 + qt * 64 + wave * 16 + quad * 4 + r;
    #pragma unroll
    for(int c = 0; c < 8; c++)
      enc[rowe * 2048 + (kv * 2 + g) * 128 + c * 16 + l15] = f2b(o_acc[c][r] * invl);
  }
}

// ---------------------------------------------------------------------------
extern "C" void kernel_launch(void* const* d_in, const int* in_sizes, int n_in,
                              void* d_out, int out_size, void* d_ws, size_t ws_size,
                              hipStream_t stream){
  const float* x     = (const float*)d_in[0];
  const int*   posi  = (const int*)  d_in[1];
  // d_in[2] = attn_mask (causal, known analytically) -- unused
  const float* w_q   = (const float*)d_in[3];
  const float* w_kv  = (const float*)d_in[4];
  const float* w_out = (const float*)d_in[5];
  float* out = (float*)d_out;

  char* w = (char*)d_ws;                        // 80 MB total
  u16* xb     = (u16*)(w);                      // 16,777,216 B (aliased by enc later)
  u16* wq_t   = (u16*)(w + 16777216);           //  8,388,608 B  [16][128][2048]
  u16* wkv_t  = (u16*)(w + 25165824);           //  8,388,608 B  [2][8][128][2048]
  u16* wout_t = (u16*)(w + 33554432);           //  8,388,608 B  [2048][2048]
  u16* q_buf  = (u16*)(w + 41943040);           // 16,777,216 B  [4096][2048]
  u16* k_buf  = (u16*)(w + 58720256);           //  8,388,608 B  [4096][1024]
  u16* v_buf  = (u16*)(w + 67108864);           //  8,388,608 B  [4096][1024]
  u16* v_t    = (u16*)(w + 75497472);           //  8,388,608 B  [2][8][128][2048]
  u16* enc    = xb;                             // xb dead after QKV GEMM

  k_cvt_x   <<<8192, 256, 0, stream>>>(x, xb);
  k_tr_f32  <<<dim3(2, 32, 16), 256, 0, stream>>>(w_q,   wq_t,   128, 2048, 262144L, 262144L);
  k_tr_f32  <<<dim3(2, 32, 16), 256, 0, stream>>>(w_kv,  wkv_t,  128, 2048, 262144L, 262144L);
  k_tr_f32  <<<dim3(32, 32, 1), 256, 0, stream>>>(w_out, wout_t, 2048, 2048, 0L, 0L);
  k_gemm_qkv<<<dim3(32, 32), 256, 0, stream>>>(xb, wq_t, wkv_t, q_buf, k_buf, v_buf);
  k_rope    <<<24576, 256, 0, stream>>>(q_buf, k_buf, posi);
  k_tr_v    <<<dim3(2, 32, 16), 256, 0, stream>>>(v_buf, v_t);
  k_flash   <<<dim3(32, 32), 256, 0, stream>>>(q_buf, k_buf, v_t, enc);
  k_gemm_out<<<dim3(32, 16), 256, 0, stream>>>(enc, wout_t, out);
}

// Round 2
// 467.184 us; speedup vs baseline: 1.3925x; 1.3925x over previous
//
#include <hip/hip_runtime.h>

// ---------------------------------------------------------------------------
// Attention (GQA + RoPE + softcap + causal) on gfx950, bf16 MFMA pipeline.
// B=2 T=2048 D=2048, NH=16 NKV=8 HD=128, softcap=50, causal.
// R2: flash rewritten — fixed-max softmax (softcap bounds logits to +-50, so
//     p=e^z is safe: no online max, no alpha rescale, no per-tile shfl),
//     Q in registers (no sQ -> 45KB LDS -> 3 blocks/CU), register-buffered
//     K/V prefetch, longest-first block order.
// ---------------------------------------------------------------------------

#define LOG2E 1.4426950408889634f

typedef unsigned short u16;
typedef __attribute__((ext_vector_type(8))) short short8;   // 8 x bf16 (4 VGPRs)
typedef __attribute__((ext_vector_type(4))) float floatx4;  // MFMA acc

static __device__ __forceinline__ u16 f2b(float f){
  unsigned u = __float_as_uint(f);
  u = (u + 0x7fffu + ((u >> 16) & 1u)) >> 16;   // RNE
  return (u16)u;
}
static __device__ __forceinline__ float b2f(u16 u){
  return __uint_as_float(((unsigned)u) << 16);
}

// ---- x fp32 -> bf16 (vectorized) ------------------------------------------
__global__ void k_cvt_x(const float* __restrict__ x, u16* __restrict__ xb){
  int i = blockIdx.x * 256 + threadIdx.x;     // exactly 2,097,152 threads
  float4 v = ((const float4*)x)[i];
  ushort4 o = make_ushort4(f2b(v.x), f2b(v.y), f2b(v.z), f2b(v.w));
  ((ushort4*)xb)[i] = o;
}

// ---- generic fp32 -> bf16 transpose (64x64 LDS tiles) ---------------------
__global__ void k_tr_f32(const float* __restrict__ src, u16* __restrict__ dst,
                         int sRS, int dRS, long sMS, long dMS){
  __shared__ float t[64][65];
  const float* s = src + (long)blockIdx.z * sMS + (long)blockIdx.y * 64 * sRS + (long)blockIdx.x * 64;
  u16* d = dst + (long)blockIdx.z * dMS + (long)blockIdx.x * 64 * dRS + (long)blockIdx.y * 64;
  int tid = threadIdx.x;
  #pragma unroll
  for(int i = 0; i < 16; i++){
    int idx = tid + 256 * i;
    t[idx >> 6][idx & 63] = s[(long)(idx >> 6) * sRS + (idx & 63)];
  }
  __syncthreads();
  #pragma unroll
  for(int i = 0; i < 16; i++){
    int idx = tid + 256 * i;
    d[(long)(idx >> 6) * dRS + (idx & 63)] = f2b(t[idx & 63][idx >> 6]);
  }
}

// ---- v transpose: v_buf[4096][1024] -> v_t[2][8][128][2048] ----------------
__global__ void k_tr_v(const u16* __restrict__ src, u16* __restrict__ dst){
  __shared__ u16 t[64][65];
  int z = blockIdx.z;                           // b*8 + kv
  const u16* s = src + ((long)(z >> 3) * 2048 + (long)blockIdx.y * 64) * 1024
                     + (z & 7) * 128 + blockIdx.x * 64;
  u16* d = dst + (long)z * 262144 + (long)blockIdx.x * 64 * 2048 + blockIdx.y * 64;
  int tid = threadIdx.x;
  #pragma unroll
  for(int i = 0; i < 16; i++){
    int idx = tid + 256 * i;
    t[idx >> 6][idx & 63] = s[(long)(idx >> 6) * 1024 + (idx & 63)];
  }
  __syncthreads();
  #pragma unroll
  for(int i = 0; i < 16; i++){
    int idx = tid + 256 * i;
    d[(long)(idx >> 6) * 2048 + (idx & 63)] = t[idx & 63][idx >> 6];
  }
}

// ---- fused QKV projection GEMM --------------------------------------------
__global__ __launch_bounds__(256) void k_gemm_qkv(
    const u16* __restrict__ A, const u16* __restrict__ wq_t, const u16* __restrict__ wkv_t,
    u16* __restrict__ qb, u16* __restrict__ kb, u16* __restrict__ vb){
  __shared__ __attribute__((aligned(16))) u16 sA[128][72];
  __shared__ __attribute__((aligned(16))) u16 sB[128][72];
  int mt = blockIdx.x, nt = blockIdx.y;
  const u16* Bt; u16* dst; int dS, dcol;
  if(nt < 16){ Bt = wq_t + (long)nt * 262144; dst = qb; dS = 2048; dcol = nt * 128; }
  else {
    Bt = wkv_t + (long)(nt - 16) * 262144;
    dS = 1024;
    if(nt < 24){ dst = kb; dcol = (nt - 16) * 128; }
    else       { dst = vb; dcol = (nt - 24) * 128; }
  }
  int tid = threadIdx.x;
  int lane = tid & 63, wave = tid >> 6, l15 = lane & 15, quad = lane >> 4;
  int ro = (wave & 1) * 64, co = (wave >> 1) * 64;
  int arow = tid >> 3, akc = tid & 7;
  const u16* Ag = A + ((long)mt * 128 + arow) * 2048 + akc * 8;
  const u16* Bg = Bt + (long)arow * 2048 + akc * 8;
  floatx4 acc[4][4];
  const floatx4 fz = {0.f, 0.f, 0.f, 0.f};
  #pragma unroll
  for(int r = 0; r < 4; r++)
    #pragma unroll
    for(int c = 0; c < 4; c++) acc[r][c] = fz;
  for(int k0 = 0; k0 < 2048; k0 += 64){
    #pragma unroll
    for(int i = 0; i < 4; i++){
      uint4 va  = *(const uint4*)(Ag + (long)(32 * i) * 2048 + k0);
      uint4 vb4 = *(const uint4*)(Bg + (long)(32 * i) * 2048 + k0);
      *(uint4*)&sA[arow + 32 * i][akc * 8] = va;
      *(uint4*)&sB[arow + 32 * i][akc * 8] = vb4;
    }
    __syncthreads();
    #pragma unroll
    for(int ks = 0; ks < 2; ks++){
      short8 af[4], bfr[4];
      #pragma unroll
      for(int r = 0; r < 4; r++) af[r]  = *(const short8*)&sA[ro + r * 16 + l15][ks * 32 + quad * 8];
      #pragma unroll
      for(int c = 0; c < 4; c++) bfr[c] = *(const short8*)&sB[co + c * 16 + l15][ks * 32 + quad * 8];
      #pragma unroll
      for(int r = 0; r < 4; r++)
        #pragma unroll
        for(int c = 0; c < 4; c++)
          acc[r][c] = __builtin_amdgcn_mfma_f32_16x16x32_bf16(af[r], bfr[c], acc[r][c], 0, 0, 0);
    }
    __syncthreads();
  }
  long rb0 = (long)mt * 128 + ro + quad * 4;
  #pragma unroll
  for(int r = 0; r < 4; r++)
    #pragma unroll
    for(int c = 0; c < 4; c++){
      int col = dcol + co + c * 16 + l15;
      #pragma unroll
      for(int j = 0; j < 4; j++)
        dst[(rb0 + r * 16 + j) * dS + col] = f2b(acc[r][c][j]);
    }
}

// ---- out projection GEMM: enc[4096x2048] x w_out -> fp32 out ---------------
__global__ __launch_bounds__(256) void k_gemm_out(
    const u16* __restrict__ A, const u16* __restrict__ Bt0, float* __restrict__ C){
  __shared__ __attribute__((aligned(16))) u16 sA[128][72];
  __shared__ __attribute__((aligned(16))) u16 sB[128][72];
  int mt = blockIdx.x, nt = blockIdx.y;
  const u16* Bt = Bt0 + (long)nt * 262144;
  int tid = threadIdx.x;
  int lane = tid & 63, wave = tid >> 6, l15 = lane & 15, quad = lane >> 4;
  int ro = (wave & 1) * 64, co = (wave >> 1) * 64;
  int arow = tid >> 3, akc = tid & 7;
  const u16* Ag = A + ((long)mt * 128 + arow) * 2048 + akc * 8;
  const u16* Bg = Bt + (long)arow * 2048 + akc * 8;
  floatx4 acc[4][4];
  const floatx4 fz = {0.f, 0.f, 0.f, 0.f};
  #pragma unroll
  for(int r = 0; r < 4; r++)
    #pragma unroll
    for(int c = 0; c < 4; c++) acc[r][c] = fz;
  for(int k0 = 0; k0 < 2048; k0 += 64){
    #pragma unroll
    for(int i = 0; i < 4; i++){
      uint4 va  = *(const uint4*)(Ag + (long)(32 * i) * 2048 + k0);
      uint4 vb4 = *(const uint4*)(Bg + (long)(32 * i) * 2048 + k0);
      *(uint4*)&sA[arow + 32 * i][akc * 8] = va;
      *(uint4*)&sB[arow + 32 * i][akc * 8] = vb4;
    }
    __syncthreads();
    #pragma unroll
    for(int ks = 0; ks < 2; ks++){
      short8 af[4], bfr[4];
      #pragma unroll
      for(int r = 0; r < 4; r++) af[r]  = *(const short8*)&sA[ro + r * 16 + l15][ks * 32 + quad * 8];
      #pragma unroll
      for(int c = 0; c < 4; c++) bfr[c] = *(const short8*)&sB[co + c * 16 + l15][ks * 32 + quad * 8];
      #pragma unroll
      for(int r = 0; r < 4; r++)
        #pragma unroll
        for(int c = 0; c < 4; c++)
          acc[r][c] = __builtin_amdgcn_mfma_f32_16x16x32_bf16(af[r], bfr[c], acc[r][c], 0, 0, 0);
    }
    __syncthreads();
  }
  long rb0 = (long)mt * 128 + ro + quad * 4;
  #pragma unroll
  for(int r = 0; r < 4; r++)
    #pragma unroll
    for(int c = 0; c < 4; c++){
      int col = nt * 128 + co + c * 16 + l15;
      #pragma unroll
      for(int j = 0; j < 4; j++)
        C[(rb0 + r * 16 + j) * 2048 + col] = acc[r][c][j];
    }
}

// ---- RoPE (q: rope + 1/sqrt(128); k: rope) in-place on bf16 ----------------
__global__ void k_rope(u16* __restrict__ qb, u16* __restrict__ kb, const int* __restrict__ pos){
  int idx = blockIdx.x * 256 + threadIdx.x;    // exactly 6,291,456 threads
  const int NQ = 4096 * 16 * 64;
  u16* p1; int row, h; float scale;
  if(idx < NQ){
    row = idx >> 10;
    int rr = idx & 1023;
    int n = rr >> 6; h = rr & 63;
    p1 = qb + (long)row * 2048 + n * 128 + h;
    scale = 0.08838834764831845f;              // HEAD_DIM^-0.5
  } else {
    int j = idx - NQ;
    row = j >> 9;
    int rr = j & 511;
    int n = rr >> 6; h = rr & 63;
    p1 = kb + (long)row * 1024 + n * 128 + h;
    scale = 1.0f;
  }
  float pf = (float)pos[row];
  float inv = exp2f(-0.20762050593045077f * (float)h);  // 10000^(-h/64)
  float ang = pf * inv;
  float sv = sinf(ang), cv = cosf(ang);
  float x1 = b2f(p1[0]), x2 = b2f(p1[64]);
  float o1 = (x1 * cv - x2 * sv) * scale;
  float o2 = (x2 * cv + x1 * sv) * scale;
  p1[0] = f2b(o1); p1[64] = f2b(o2);
}

// ---- flash attention v2 ----------------------------------------------------
// Q-tile 64 (4 waves x 16 rows), K-tile 64, causal, fixed-max softmax.
// Softcap guarantees z in [-50,50] => p=e^z never under/overflows fp32/bf16.
// Q fragments in regs; K/V register-buffered prefetch; 45KB LDS = 3 blocks/CU.
__global__ __launch_bounds__(256, 3) void k_flash(
    const u16* __restrict__ qb, const u16* __restrict__ kb,
    const u16* __restrict__ vt, u16* __restrict__ enc){
  __shared__ __attribute__((aligned(16))) u16 sK[64][136];
  __shared__ __attribute__((aligned(16))) u16 sVt[128][72];
  __shared__ __attribute__((aligned(16))) u16 sP[4][16][72];
  int qt = 31 - blockIdx.y;                    // longest blocks dispatch first
  int hidx = blockIdx.x;
  int b = hidx >> 4, kv = (hidx >> 1) & 7, g = hidx & 1;
  int tid = threadIdx.x;
  int lane = tid & 63, wave = tid >> 6, l15 = lane & 15, quad = lane >> 4;

  // Q fragments (A-layout: lane(l15,quad) holds Q[wave*16+l15][ks*32+quad*8+j])
  short8 qf[4];
  {
    const u16* qg = qb + ((long)b * 2048 + qt * 64 + wave * 16 + l15) * 2048
                       + (kv * 2 + g) * 128 + quad * 8;
    #pragma unroll
    for(int ks = 0; ks < 4; ks++) qf[ks] = *(const short8*)(qg + ks * 32);
  }

  // staging coords
  int rr = tid >> 4, hc = tid & 15;            // K: rows rr+16i, cols hc*8
  int hr = tid >> 3, sc = tid & 7;             // Vt: rows hr+32i, cols sc*8
  const u16* kbase = kb + ((long)b * 2048 + rr) * 1024 + kv * 128 + hc * 8;
  const u16* vbase = vt + ((long)(b * 8 + kv) * 128 + hr) * 2048 + sc * 8;

  uint4 kreg[4], vreg[4];
  #pragma unroll
  for(int i = 0; i < 4; i++){                  // preload tile 0
    kreg[i] = *(const uint4*)(kbase + (long)(16 * i) * 1024);
    vreg[i] = *(const uint4*)(vbase + (long)(32 * i) * 2048);
  }

  float l_loc[4] = {0.f, 0.f, 0.f, 0.f};
  floatx4 o_acc[8];
  const floatx4 fz = {0.f, 0.f, 0.f, 0.f};
  #pragma unroll
  for(int c = 0; c < 8; c++) o_acc[c] = fz;

  const float c1 = 0.057707801635558536f;      // 2*log2(e)/50
  const float c2 = -144.26950408889634f;       // -100*log2(e)
  const float c3 = 72.13475204444817f;         // 50*log2(e)

  for(int kt = 0; kt <= qt; kt++){
    if(kt > 0) __syncthreads();                // previous tile's readers done
    #pragma unroll
    for(int i = 0; i < 4; i++){
      *(uint4*)&sK[rr + 16 * i][hc * 8] = kreg[i];
      *(uint4*)&sVt[hr + 32 * i][sc * 8] = vreg[i];
    }
    __syncthreads();
    if(kt < qt){                               // prefetch next tile (lands during compute)
      #pragma unroll
      for(int i = 0; i < 4; i++){
        kreg[i] = *(const uint4*)(kbase + (long)((kt + 1) * 64 + 16 * i) * 1024);
        vreg[i] = *(const uint4*)(vbase + (kt + 1) * 64 + (long)(32 * i) * 2048);
      }
    }
    // S = Q K^T
    floatx4 s_acc[4];
    #pragma unroll
    for(int c = 0; c < 4; c++) s_acc[c] = fz;
    #pragma unroll
    for(int ks = 0; ks < 4; ks++){
      #pragma unroll
      for(int cb = 0; cb < 4; cb++){
        short8 bk = *(const short8*)&sK[cb * 16 + l15][ks * 32 + quad * 8];
        s_acc[cb] = __builtin_amdgcn_mfma_f32_16x16x32_bf16(qf[ks], bk, s_acc[cb], 0, 0, 0);
      }
    }
    // p = exp(50*tanh(s/50)) = exp2(c2/(u+1) + c3), u = exp2(c1*s)
    bool diag = (kt == qt);
    int rloc = wave * 16 + quad * 4;           // query row within tile (quad*4+r)
    #pragma unroll
    for(int r = 0; r < 4; r++){
      #pragma unroll
      for(int cb = 0; cb < 4; cb++){
        float s = s_acc[cb][r];
        float u = __builtin_amdgcn_exp2f(c1 * s);
        float d = __builtin_amdgcn_rcpf(u + 1.f);
        float p = __builtin_amdgcn_exp2f(__builtin_fmaf(c2, d, c3));
        if(diag && (cb * 16 + l15 > rloc + r)) p = 0.f;
        l_loc[r] += p;
        sP[wave][quad * 4 + r][cb * 16 + l15] = f2b(p);
      }
    }
    // O += P V
    #pragma unroll
    for(int ks2 = 0; ks2 < 2; ks2++){
      short8 ap = *(const short8*)&sP[wave][l15][ks2 * 32 + quad * 8];
      #pragma unroll
      for(int c = 0; c < 8; c++){
        short8 bv = *(const short8*)&sVt[c * 16 + l15][ks2 * 32 + quad * 8];
        o_acc[c] = __builtin_amdgcn_mfma_f32_16x16x32_bf16(ap, bv, o_acc[c], 0, 0, 0);
      }
    }
  }
  // single end-of-loop row-sum reduction across the 16 column lanes
  #pragma unroll
  for(int r = 0; r < 4; r++){
    float l = l_loc[r];
    #pragma unroll
    for(int off = 1; off < 16; off <<= 1) l += __shfl_xor(l, off);
    float invl = 1.f / l;
    long rowe = (long)b * 2048 + qt * 64 + wave * 16 + quad * 4 + r;
    #pragma unroll
    for(int c = 0; c < 8; c++)
      enc[rowe * 2048 + (kv * 2 + g) * 128 + c * 16 + l15] = f2b(o_acc[c][r] * invl);
  }
}

// ---------------------------------------------------------------------------
extern "C" void kernel_launch(void* const* d_in, const int* in_sizes, int n_in,
                              void* d_out, int out_size, void* d_ws, size_t ws_size,
                              hipStream_t stream){
  const float* x     = (const float*)d_in[0];
  const int*   posi  = (const int*)  d_in[1];
  // d_in[2] = attn_mask (causal, known analytically) -- unused
  const float* w_q   = (const float*)d_in[3];
  const float* w_kv  = (const float*)d_in[4];
  const float* w_out = (const float*)d_in[5];
  float* out = (float*)d_out;

  char* w = (char*)d_ws;                        // 80 MB total
  u16* xb     = (u16*)(w);                      // 16,777,216 B (aliased by enc later)
  u16* wq_t   = (u16*)(w + 16777216);           //  8,388,608 B  [16][128][2048]
  u16* wkv_t  = (u16*)(w + 25165824);           //  8,388,608 B  [2][8][128][2048]
  u16* wout_t = (u16*)(w + 33554432);           //  8,388,608 B  [2048][2048]
  u16* q_buf  = (u16*)(w + 41943040);           // 16,777,216 B  [4096][2048]
  u16* k_buf  = (u16*)(w + 58720256);           //  8,388,608 B  [4096][1024]
  u16* v_buf  = (u16*)(w + 67108864);           //  8,388,608 B  [4096][1024]
  u16* v_t    = (u16*)(w + 75497472);           //  8,388,608 B  [2][8][128][2048]
  u16* enc    = xb;                             // xb dead after QKV GEMM

  k_cvt_x   <<<8192, 256, 0, stream>>>(x, xb);
  k_tr_f32  <<<dim3(2, 32, 16), 256, 0, stream>>>(w_q,   wq_t,   128, 2048, 262144L, 262144L);
  k_tr_f32  <<<dim3(2, 32, 16), 256, 0, stream>>>(w_kv,  wkv_t,  128, 2048, 262144L, 262144L);
  k_tr_f32  <<<dim3(32, 32, 1), 256, 0, stream>>>(w_out, wout_t, 2048, 2048, 0L, 0L);
  k_gemm_qkv<<<dim3(32, 32), 256, 0, stream>>>(xb, wq_t, wkv_t, q_buf, k_buf, v_buf);
  k_rope    <<<24576, 256, 0, stream>>>(q_buf, k_buf, posi);
  k_tr_v    <<<dim3(2, 32, 16), 256, 0, stream>>>(v_buf, v_t);
  k_flash   <<<dim3(32, 32), 256, 0, stream>>>(q_buf, k_buf, v_t, enc);
  k_gemm_out<<<dim3(32, 16), 256, 0, stream>>>(enc, wout_t, out);
}

// Round 3
// 355.970 us; speedup vs baseline: 1.8276x; 1.3124x over previous
//
#include <hip/hip_runtime.h>

// ---------------------------------------------------------------------------
// Attention (GQA + RoPE + softcap + causal) on gfx950, bf16 MFMA pipeline.
// B=2 T=2048 D=2048, NH=16 NKV=8 HD=128, softcap=50, causal.
// R3: global_load_lds staging everywhere (m97 pattern) with XOR-swizzled
//     unpadded LDS; flash double-buffers K/V with one barrier per tile
//     (no register prefetch -> no spill; R2's launch_bounds(256,3) caused
//     ~450MB scratch spill traffic); RoPE uses precomputed sin/cos table.
// ---------------------------------------------------------------------------

typedef unsigned short u16;
typedef __attribute__((ext_vector_type(8))) short short8;   // 8 x bf16 (4 VGPRs)
typedef __attribute__((ext_vector_type(4))) float floatx4;  // MFMA acc

static __device__ __forceinline__ u16 f2b(float f){
  unsigned u = __float_as_uint(f);
  u = (u + 0x7fffu + ((u >> 16) & 1u)) >> 16;   // RNE
  return (u16)u;
}
static __device__ __forceinline__ float b2f(u16 u){
  return __uint_as_float(((unsigned)u) << 16);
}
// async global->LDS DMA, 16B per lane; LDS dest = wave-uniform base + lane*16
static __device__ __forceinline__ void gload16(const u16* g, u16* l){
  __builtin_amdgcn_global_load_lds(
      (const __attribute__((address_space(1))) unsigned int*)g,
      (__attribute__((address_space(3))) unsigned int*)l, 16, 0, 0);
}

// ---- x fp32 -> bf16 (vectorized) ------------------------------------------
__global__ void k_cvt_x(const float* __restrict__ x, u16* __restrict__ xb){
  int i = blockIdx.x * 256 + threadIdx.x;     // exactly 2,097,152 threads
  float4 v = ((const float4*)x)[i];
  ushort4 o = make_ushort4(f2b(v.x), f2b(v.y), f2b(v.z), f2b(v.w));
  ((ushort4*)xb)[i] = o;
}

// ---- generic fp32 -> bf16 transpose (64x64 LDS tiles) ---------------------
__global__ void k_tr_f32(const float* __restrict__ src, u16* __restrict__ dst,
                         int sRS, int dRS, long sMS, long dMS){
  __shared__ float t[64][65];
  const float* s = src + (long)blockIdx.z * sMS + (long)blockIdx.y * 64 * sRS + (long)blockIdx.x * 64;
  u16* d = dst + (long)blockIdx.z * dMS + (long)blockIdx.x * 64 * dRS + (long)blockIdx.y * 64;
  int tid = threadIdx.x;
  #pragma unroll
  for(int i = 0; i < 16; i++){
    int idx = tid + 256 * i;
    t[idx >> 6][idx & 63] = s[(long)(idx >> 6) * sRS + (idx & 63)];
  }
  __syncthreads();
  #pragma unroll
  for(int i = 0; i < 16; i++){
    int idx = tid + 256 * i;
    d[(long)(idx >> 6) * dRS + (idx & 63)] = f2b(t[idx & 63][idx >> 6]);
  }
}

// ---- v transpose: v_buf[4096][1024] -> v_t[2][8][128][2048] ----------------
__global__ void k_tr_v(const u16* __restrict__ src, u16* __restrict__ dst){
  __shared__ u16 t[64][65];
  int z = blockIdx.z;                           // b*8 + kv
  const u16* s = src + ((long)(z >> 3) * 2048 + (long)blockIdx.y * 64) * 1024
                     + (z & 7) * 128 + blockIdx.x * 64;
  u16* d = dst + (long)z * 262144 + (long)blockIdx.x * 64 * 2048 + blockIdx.y * 64;
  int tid = threadIdx.x;
  #pragma unroll
  for(int i = 0; i < 16; i++){
    int idx = tid + 256 * i;
    t[idx >> 6][idx & 63] = s[(long)(idx >> 6) * 1024 + (idx & 63)];
  }
  __syncthreads();
  #pragma unroll
  for(int i = 0; i < 16; i++){
    int idx = tid + 256 * i;
    d[(long)(idx >> 6) * 2048 + (idx & 63)] = t[idx & 63][idx >> 6];
  }
}

// ---- fused QKV projection GEMM (global_load_lds + XOR swizzle) -------------
__global__ __launch_bounds__(256) void k_gemm_qkv(
    const u16* __restrict__ A, const u16* __restrict__ wq_t, const u16* __restrict__ wkv_t,
    u16* __restrict__ qb, u16* __restrict__ kb, u16* __restrict__ vb){
  __shared__ __attribute__((aligned(16))) u16 sA[128 * 64];   // 16 KB, 64 elts/row
  __shared__ __attribute__((aligned(16))) u16 sB[128 * 64];
  int mt = blockIdx.x, nt = blockIdx.y;
  const u16* Bt; u16* dst; int dS, dcol;
  if(nt < 16){ Bt = wq_t + (long)nt * 262144; dst = qb; dS = 2048; dcol = nt * 128; }
  else {
    Bt = wkv_t + (long)(nt - 16) * 262144;
    dS = 1024;
    if(nt < 24){ dst = kb; dcol = (nt - 16) * 128; }
    else       { dst = vb; dcol = (nt - 24) * 128; }
  }
  int tid = threadIdx.x;
  int lane = tid & 63, wave = tid >> 6, l15 = lane & 15, quad = lane >> 4;
  int ro = (wave & 1) * 64, co = (wave >> 1) * 64;
  int xm7 = l15 & 7;                             // row&7 of every fragment row
  // staging: LDS chunk c of row r holds global chunk c^(r&7)
  int srow = tid >> 3;                           // 0..31 (+32/round)
  int gch  = (tid & 7) ^ (srow & 7);
  const u16* Ag = A  + ((long)(mt * 128) + srow) * 2048 + (gch << 3);
  const u16* Bg = Bt + (long)srow * 2048 + (gch << 3);
  u16* lA = sA + tid * 8;
  u16* lB = sB + tid * 8;
  floatx4 acc[4][4];
  const floatx4 fz = {0.f, 0.f, 0.f, 0.f};
  #pragma unroll
  for(int r = 0; r < 4; r++)
    #pragma unroll
    for(int c = 0; c < 4; c++) acc[r][c] = fz;
  for(int k0 = 0; k0 < 2048; k0 += 64){
    #pragma unroll
    for(int r = 0; r < 4; r++){
      gload16(Ag + (long)r * 65536 + k0, lA + r * 2048);
      gload16(Bg + (long)r * 65536 + k0, lB + r * 2048);
    }
    __syncthreads();
    #pragma unroll
    for(int ks = 0; ks < 2; ks++){
      short8 af[4], bfr[4];
      #pragma unroll
      for(int r = 0; r < 4; r++)
        af[r]  = *(const short8*)(sA + ((ro + r * 16 + l15) << 6) + ((((ks << 2) | quad) ^ xm7) << 3));
      #pragma unroll
      for(int c = 0; c < 4; c++)
        bfr[c] = *(const short8*)(sB + ((co + c * 16 + l15) << 6) + ((((ks << 2) | quad) ^ xm7) << 3));
      #pragma unroll
      for(int r = 0; r < 4; r++)
        #pragma unroll
        for(int c = 0; c < 4; c++)
          acc[r][c] = __builtin_amdgcn_mfma_f32_16x16x32_bf16(af[r], bfr[c], acc[r][c], 0, 0, 0);
    }
    __syncthreads();
  }
  long rb0 = (long)mt * 128 + ro + quad * 4;     // C layout: row=quad*4+reg, col=l15
  #pragma unroll
  for(int r = 0; r < 4; r++)
    #pragma unroll
    for(int c = 0; c < 4; c++){
      int col = dcol + co + c * 16 + l15;
      #pragma unroll
      for(int j = 0; j < 4; j++)
        dst[(rb0 + r * 16 + j) * dS + col] = f2b(acc[r][c][j]);
    }
}

// ---- out projection GEMM: enc[4096x2048] x w_out^T -> fp32 out -------------
__global__ __launch_bounds__(256) void k_gemm_out(
    const u16* __restrict__ A, const u16* __restrict__ Bt0, float* __restrict__ C){
  __shared__ __attribute__((aligned(16))) u16 sA[128 * 64];
  __shared__ __attribute__((aligned(16))) u16 sB[128 * 64];
  int mt = blockIdx.x, nt = blockIdx.y;
  const u16* Bt = Bt0 + (long)nt * 262144;
  int tid = threadIdx.x;
  int lane = tid & 63, wave = tid >> 6, l15 = lane & 15, quad = lane >> 4;
  int ro = (wave & 1) * 64, co = (wave >> 1) * 64;
  int xm7 = l15 & 7;
  int srow = tid >> 3;
  int gch  = (tid & 7) ^ (srow & 7);
  const u16* Ag = A  + ((long)(mt * 128) + srow) * 2048 + (gch << 3);
  const u16* Bg = Bt + (long)srow * 2048 + (gch << 3);
  u16* lA = sA + tid * 8;
  u16* lB = sB + tid * 8;
  floatx4 acc[4][4];
  const floatx4 fz = {0.f, 0.f, 0.f, 0.f};
  #pragma unroll
  for(int r = 0; r < 4; r++)
    #pragma unroll
    for(int c = 0; c < 4; c++) acc[r][c] = fz;
  for(int k0 = 0; k0 < 2048; k0 += 64){
    #pragma unroll
    for(int r = 0; r < 4; r++){
      gload16(Ag + (long)r * 65536 + k0, lA + r * 2048);
      gload16(Bg + (long)r * 65536 + k0, lB + r * 2048);
    }
    __syncthreads();
    #pragma unroll
    for(int ks = 0; ks < 2; ks++){
      short8 af[4], bfr[4];
      #pragma unroll
      for(int r = 0; r < 4; r++)
        af[r]  = *(const short8*)(sA + ((ro + r * 16 + l15) << 6) + ((((ks << 2) | quad) ^ xm7) << 3));
      #pragma unroll
      for(int c = 0; c < 4; c++)
        bfr[c] = *(const short8*)(sB + ((co + c * 16 + l15) << 6) + ((((ks << 2) | quad) ^ xm7) << 3));
      #pragma unroll
      for(int r = 0; r < 4; r++)
        #pragma unroll
        for(int c = 0; c < 4; c++)
          acc[r][c] = __builtin_amdgcn_mfma_f32_16x16x32_bf16(af[r], bfr[c], acc[r][c], 0, 0, 0);
    }
    __syncthreads();
  }
  long rb0 = (long)mt * 128 + ro + quad * 4;
  #pragma unroll
  for(int r = 0; r < 4; r++)
    #pragma unroll
    for(int c = 0; c < 4; c++){
      int col = nt * 128 + co + c * 16 + l15;
      #pragma unroll
      for(int j = 0; j < 4; j++)
        C[(rb0 + r * 16 + j) * 2048 + col] = acc[r][c][j];
    }
}

// ---- sin/cos table: tab[row][h]=sin, tab[row][64+h]=cos (row<4096,h<64) ----
__global__ void k_sincos(const int* __restrict__ pos, float* __restrict__ tab){
  int idx = blockIdx.x * 256 + threadIdx.x;     // 262,144 threads
  int row = idx >> 6, h = idx & 63;
  float pf = (float)pos[row];
  float inv = exp2f(-0.20762050593045077f * (float)h);  // 10000^(-h/64)
  float ang = pf * inv;
  tab[(row << 7) + h]      = sinf(ang);
  tab[(row << 7) + 64 + h] = cosf(ang);
}

// ---- RoPE (q: rope + 1/sqrt(128); k: rope) in-place on bf16 ----------------
__global__ void k_rope(u16* __restrict__ qb, u16* __restrict__ kb,
                       const float* __restrict__ tab){
  int idx = blockIdx.x * 256 + threadIdx.x;    // exactly 6,291,456 threads
  const int NQ = 4096 * 16 * 64;
  u16* p1; int row, h; float scale;
  if(idx < NQ){
    row = idx >> 10;
    int rr = idx & 1023;
    int n = rr >> 6; h = rr & 63;
    p1 = qb + (long)row * 2048 + n * 128 + h;
    scale = 0.08838834764831845f;              // HEAD_DIM^-0.5
  } else {
    int j = idx - NQ;
    row = j >> 9;
    int rr = j & 511;
    int n = rr >> 6; h = rr & 63;
    p1 = kb + (long)row * 1024 + n * 128 + h;
    scale = 1.0f;
  }
  float sv = tab[(row << 7) + h], cv = tab[(row << 7) + 64 + h];
  float x1 = b2f(p1[0]), x2 = b2f(p1[64]);
  float o1 = (x1 * cv - x2 * sv) * scale;
  float o2 = (x2 * cv + x1 * sv) * scale;
  p1[0] = f2b(o1); p1[64] = f2b(o2);
}

// ---- flash attention v3 ----------------------------------------------------
// Q-tile 64 (4 waves x 16 rows), K-tile 64, causal, fixed-max softmax
// (softcap bounds z to [-50,50] so p=e^z is safe). K/V staged by
// global_load_lds into double-buffered XOR-swizzled LDS; one barrier/tile;
// DMA for tile kt+1 flies during compute of tile kt.
__global__ __launch_bounds__(256) void k_flash(
    const u16* __restrict__ qb, const u16* __restrict__ kb,
    const u16* __restrict__ vt, u16* __restrict__ enc){
  __shared__ __attribute__((aligned(16))) u16 sK[2 * 64 * 128];   // 32 KB, 128 elts/row
  __shared__ __attribute__((aligned(16))) u16 sVt[2 * 128 * 64];  // 32 KB, 64 elts/row
  __shared__ __attribute__((aligned(16))) u16 sP[4][16][72];      // 9 KB
  int qt = 31 - blockIdx.y;                    // longest blocks dispatch first
  int hidx = blockIdx.x;
  int b = hidx >> 4, kv = (hidx >> 1) & 7, g = hidx & 1;
  int tid = threadIdx.x;
  int lane = tid & 63, wave = tid >> 6, l15 = lane & 15, quad = lane >> 4;

  // Q fragments (A-layout: lane(l15,quad) holds Q[wave*16+l15][ks*32+quad*8+j])
  short8 qf[4];
  {
    const u16* qg = qb + ((long)b * 2048 + qt * 64 + wave * 16 + l15) * 2048
                       + (kv * 2 + g) * 128 + quad * 8;
    #pragma unroll
    for(int ks = 0; ks < 4; ks++) qf[ks] = *(const short8*)(qg + ks * 32);
  }

  // staging: K rows 256B (16 chunks, swizzle by row&15); Vt rows 128B (8 chunks, row&7)
  int krow = tid >> 4;                          // 0..15 (+16/round)
  int kch  = (tid & 15) ^ krow;
  const u16* Kg = kb + ((long)b * 2048 + krow) * 1024 + kv * 128 + (kch << 3);
  int vrow = tid >> 3;                          // 0..31 (+32/round)
  int vch  = (tid & 7) ^ (vrow & 7);
  const u16* Vg = vt + ((long)(b * 8 + kv) * 128 + vrow) * 2048 + (vch << 3);
  u16* lK = sK  + tid * 8;
  u16* lV = sVt + tid * 8;
  #pragma unroll
  for(int r = 0; r < 4; r++){                   // preload tile 0 -> buf 0
    gload16(Kg + (long)r * 16384, lK + r * 2048);
    gload16(Vg + (long)r * 65536, lV + r * 2048);
  }

  float l_loc[4] = {0.f, 0.f, 0.f, 0.f};
  floatx4 o_acc[8];
  const floatx4 fz = {0.f, 0.f, 0.f, 0.f};
  #pragma unroll
  for(int c = 0; c < 8; c++) o_acc[c] = fz;

  const float c1 = 0.057707801635558536f;      // 2*log2(e)/50
  const float c2 = -144.26950408889634f;       // -100*log2(e)
  const float c3 = 72.13475204444817f;         // 50*log2(e)

  for(int kt = 0; kt <= qt; kt++){
    int buf = (kt & 1) * 8192;
    __syncthreads();                           // drains DMAs for this buf + frees other buf
    if(kt < qt){                               // async stage tile kt+1 into other buf
      int nb = buf ^ 8192;
      #pragma unroll
      for(int r = 0; r < 4; r++){
        gload16(Kg + (long)(kt + 1) * 65536 + (long)r * 16384, lK + nb + r * 2048);
        gload16(Vg + (kt + 1) * 64 + (long)r * 65536, lV + nb + r * 2048);
      }
    }
    // S = Q K^T
    floatx4 s_acc[4];
    #pragma unroll
    for(int c = 0; c < 4; c++) s_acc[c] = fz;
    #pragma unroll
    for(int ks = 0; ks < 4; ks++){
      #pragma unroll
      for(int cb = 0; cb < 4; cb++){
        short8 bk = *(const short8*)(sK + buf + ((cb * 16 + l15) << 7)
                                     + ((((ks << 2) | quad) ^ l15) << 3));
        s_acc[cb] = __builtin_amdgcn_mfma_f32_16x16x32_bf16(qf[ks], bk, s_acc[cb], 0, 0, 0);
      }
    }
    // p = exp(50*tanh(s/50)) = exp2(c2/(u+1) + c3), u = exp2(c1*s)
    bool diag = (kt == qt);
    int rloc = wave * 16 + quad * 4;
    #pragma unroll
    for(int r = 0; r < 4; r++){
      #pragma unroll
      for(int cb = 0; cb < 4; cb++){
        float s = s_acc[cb][r];
        float u = __builtin_amdgcn_exp2f(c1 * s);
        float d = __builtin_amdgcn_rcpf(u + 1.f);
        float p = __builtin_amdgcn_exp2f(__builtin_fmaf(c2, d, c3));
        if(diag && (cb * 16 + l15 > rloc + r)) p = 0.f;
        l_loc[r] += p;
        sP[wave][quad * 4 + r][cb * 16 + l15] = f2b(p);
      }
    }
    // O += P V
    #pragma unroll
    for(int ks2 = 0; ks2 < 2; ks2++){
      short8 ap = *(const short8*)&sP[wave][l15][ks2 * 32 + quad * 8];
      #pragma unroll
      for(int c = 0; c < 8; c++){
        short8 bv = *(const short8*)(sVt + buf + ((c * 16 + l15) << 6)
                                     + ((((ks2 << 2) | quad) ^ (l15 & 7)) << 3));
        o_acc[c] = __builtin_amdgcn_mfma_f32_16x16x32_bf16(ap, bv, o_acc[c], 0, 0, 0);
      }
    }
  }
  // single end-of-loop row-sum reduction across the 16 column lanes
  #pragma unroll
  for(int r = 0; r < 4; r++){
    float l = l_loc[r];
    #pragma unroll
    for(int off = 1; off < 16; off <<= 1) l += __shfl_xor(l, off);
    float invl = 1.f / l;
    long rowe = (long)b * 2048 + qt * 64 + wave * 16 + quad * 4 + r;
    #pragma unroll
    for(int c = 0; c < 8; c++)
      enc[rowe * 2048 + (kv * 2 + g) * 128 + c * 16 + l15] = f2b(o_acc[c][r] * invl);
  }
}

// ---------------------------------------------------------------------------
extern "C" void kernel_launch(void* const* d_in, const int* in_sizes, int n_in,
                              void* d_out, int out_size, void* d_ws, size_t ws_size,
                              hipStream_t stream){
  const float* x     = (const float*)d_in[0];
  const int*   posi  = (const int*)  d_in[1];
  // d_in[2] = attn_mask (causal, known analytically) -- unused
  const float* w_q   = (const float*)d_in[3];
  const float* w_kv  = (const float*)d_in[4];
  const float* w_out = (const float*)d_in[5];
  float* out = (float*)d_out;

  char* w = (char*)d_ws;                        // ~84 MB total
  u16* xb     = (u16*)(w);                      // 16,777,216 B (reused: sincos tab, then enc)
  u16* wq_t   = (u16*)(w + 16777216);           //  8,388,608 B  [16][128][2048]
  u16* wkv_t  = (u16*)(w + 25165824);           //  8,388,608 B  [2][8][128][2048]
  u16* wout_t = (u16*)(w + 33554432);           //  8,388,608 B  [2048][2048]
  u16* q_buf  = (u16*)(w + 41943040);           // 16,777,216 B  [4096][2048]
  u16* k_buf  = (u16*)(w + 58720256);           //  8,388,608 B  [4096][1024]
  u16* v_buf  = (u16*)(w + 67108864);           //  8,388,608 B  [4096][1024]
  u16* v_t    = (u16*)(w + 75497472);           //  8,388,608 B  [2][8][128][2048]
  float* tab  = (float*)(w);                    //  2,097,152 B (xb dead after QKV GEMM)
  u16* enc    = xb;                             // tab dead after rope

  k_cvt_x   <<<8192, 256, 0, stream>>>(x, xb);
  k_tr_f32  <<<dim3(2, 32, 16), 256, 0, stream>>>(w_q,   wq_t,   128, 2048, 262144L, 262144L);
  k_tr_f32  <<<dim3(2, 32, 16), 256, 0, stream>>>(w_kv,  wkv_t,  128, 2048, 262144L, 262144L);
  k_tr_f32  <<<dim3(32, 32, 1), 256, 0, stream>>>(w_out, wout_t, 2048, 2048, 0L, 0L);
  k_gemm_qkv<<<dim3(32, 32), 256, 0, stream>>>(xb, wq_t, wkv_t, q_buf, k_buf, v_buf);
  k_sincos  <<<1024, 256, 0, stream>>>(posi, tab);
  k_rope    <<<24576, 256, 0, stream>>>(q_buf, k_buf, tab);
  k_tr_v    <<<dim3(2, 32, 16), 256, 0, stream>>>(v_buf, v_t);
  k_flash   <<<dim3(32, 32), 256, 0, stream>>>(q_buf, k_buf, v_t, enc);
  k_gemm_out<<<dim3(32, 16), 256, 0, stream>>>(enc, wout_t, out);
}

// Round 4
// 332.979 us; speedup vs baseline: 1.9538x; 1.0690x over previous
//
#include <hip/hip_runtime.h>

// ---------------------------------------------------------------------------
// Attention (GQA + RoPE + softcap + causal) on gfx950, bf16 MFMA pipeline.
// B=2 T=2048 D=2048, NH=16 NKV=8 HD=128, softcap=50, causal.
// R4: 4 kernels total. k_prep = cvt_x + 3 weight transposes + sincos table.
//     k_gemm_qkv fuses RoPE (q,k) and V-transpose into its epilogue via a
//     +132-padded LDS tile (reuses staging pool). Flash: diag/non-diag split.
// ---------------------------------------------------------------------------

typedef unsigned short u16;
typedef __attribute__((ext_vector_type(8))) short short8;   // 8 x bf16 (4 VGPRs)
typedef __attribute__((ext_vector_type(4))) float floatx4;  // MFMA acc

static __device__ __forceinline__ u16 f2b(float f){
  unsigned u = __float_as_uint(f);
  u = (u + 0x7fffu + ((u >> 16) & 1u)) >> 16;   // RNE
  return (u16)u;
}
static __device__ __forceinline__ float b2f(u16 u){
  return __uint_as_float(((unsigned)u) << 16);
}
// async global->LDS DMA, 16B per lane; LDS dest = wave-uniform base + lane*16
static __device__ __forceinline__ void gload16(const u16* g, u16* l){
  __builtin_amdgcn_global_load_lds(
      (const __attribute__((address_space(1))) unsigned int*)g,
      (__attribute__((address_space(3))) unsigned int*)l, 16, 0, 0);
}

// ---- prep: x->bf16 | w_q/w_kv/w_out transpose->B^T bf16 | sin/cos table ----
static __device__ void tr64(const float* __restrict__ s, u16* __restrict__ d,
                            int sRS, int dRS, float (*t)[65], int tid){
  #pragma unroll
  for(int i = 0; i < 16; i++){
    int idx = tid + 256 * i;
    t[idx >> 6][idx & 63] = s[(long)(idx >> 6) * sRS + (idx & 63)];
  }
  __syncthreads();
  #pragma unroll
  for(int i = 0; i < 16; i++){
    int idx = tid + 256 * i;
    d[(long)(idx >> 6) * dRS + (idx & 63)] = f2b(t[idx & 63][idx >> 6]);
  }
}

__global__ __launch_bounds__(256) void k_prep(
    const float* __restrict__ x, u16* __restrict__ xb,
    const float* __restrict__ wq, u16* __restrict__ wq_t,
    const float* __restrict__ wkv, u16* __restrict__ wkv_t,
    const float* __restrict__ wo, u16* __restrict__ wo_t,
    const int* __restrict__ pos, float* __restrict__ tab){
  __shared__ float t[64][65];
  int blk = blockIdx.x, tid = threadIdx.x;
  if(blk < 8192){                               // x fp32 -> bf16
    int i = blk * 256 + tid;
    float4 v = ((const float4*)x)[i];
    ushort4 o = make_ushort4(f2b(v.x), f2b(v.y), f2b(v.z), f2b(v.w));
    ((ushort4*)xb)[i] = o;
  } else if(blk < 9216){                        // w_q [16][2048][128] -> [16][128][2048]
    int q = blk - 8192;
    int bx = q & 1, by = (q >> 1) & 31, bz = q >> 6;
    tr64(wq + (long)bz * 262144 + (long)by * 64 * 128 + bx * 64,
         wq_t + (long)bz * 262144 + (long)bx * 64 * 2048 + by * 64, 128, 2048, t, tid);
  } else if(blk < 10240){                       // w_kv [16][2048][128] -> [16][128][2048]
    int q = blk - 9216;
    int bx = q & 1, by = (q >> 1) & 31, bz = q >> 6;
    tr64(wkv + (long)bz * 262144 + (long)by * 64 * 128 + bx * 64,
         wkv_t + (long)bz * 262144 + (long)bx * 64 * 2048 + by * 64, 128, 2048, t, tid);
  } else if(blk < 11264){                       // w_out [2048][2048] -> transpose
    int q = blk - 10240;
    int bx = q & 31, by = q >> 5;
    tr64(wo + (long)by * 64 * 2048 + bx * 64,
         wo_t + (long)bx * 64 * 2048 + by * 64, 2048, 2048, t, tid);
  } else {                                      // sin/cos: tab[row][0:64]=sin, [64:128]=cos
    int idx = (blk - 11264) * 256 + tid;        // 262,144 = 4096 rows x 64 h
    int row = idx >> 6, h = idx & 63;
    float pf = (float)pos[row];
    float inv = exp2f(-0.20762050593045077f * (float)h);  // 10000^(-h/64)
    float ang = pf * inv;
    tab[(row << 7) + h]      = sinf(ang);
    tab[(row << 7) + 64 + h] = cosf(ang);
  }
}

// ---- fused QKV projection GEMM + RoPE + V-transpose epilogue ---------------
// nt<16 -> q head nt ; 16..23 -> k head nt-16 ; 24..31 -> v head nt-24.
__global__ __launch_bounds__(256) void k_gemm_qkv(
    const u16* __restrict__ A, const u16* __restrict__ wq_t, const u16* __restrict__ wkv_t,
    const float* __restrict__ tab,
    u16* __restrict__ qb, u16* __restrict__ kb, u16* __restrict__ vtp){
  __shared__ __attribute__((aligned(16))) u16 pool[128 * 132]; // staging 32KB | epi tile
  u16* sA = pool;                               // [128][64]
  u16* sB = pool + 8192;                        // [128][64]
  int mt = blockIdx.x, nt = blockIdx.y;
  const u16* Bt = (nt < 16) ? (wq_t + (long)nt * 262144)
                            : (wkv_t + (long)(nt - 16) * 262144);
  int tid = threadIdx.x;
  int lane = tid & 63, wave = tid >> 6, l15 = lane & 15, quad = lane >> 4;
  int ro = (wave & 1) * 64, co = (wave >> 1) * 64;
  int xm7 = l15 & 7;
  int srow = tid >> 3;
  int gch  = (tid & 7) ^ (srow & 7);            // XOR-swizzled staging chunks
  const u16* Ag = A  + ((long)(mt * 128) + srow) * 2048 + (gch << 3);
  const u16* Bg = Bt + (long)srow * 2048 + (gch << 3);
  u16* lA = sA + tid * 8;
  u16* lB = sB + tid * 8;
  floatx4 acc[4][4];
  const floatx4 fz = {0.f, 0.f, 0.f, 0.f};
  #pragma unroll
  for(int r = 0; r < 4; r++)
    #pragma unroll
    for(int c = 0; c < 4; c++) acc[r][c] = fz;
  for(int k0 = 0; k0 < 2048; k0 += 64){
    #pragma unroll
    for(int r = 0; r < 4; r++){
      gload16(Ag + (long)r * 65536 + k0, lA + r * 2048);
      gload16(Bg + (long)r * 65536 + k0, lB + r * 2048);
    }
    __syncthreads();
    #pragma unroll
    for(int ks = 0; ks < 2; ks++){
      short8 af[4], bfr[4];
      #pragma unroll
      for(int r = 0; r < 4; r++)
        af[r]  = *(const short8*)(sA + ((ro + r * 16 + l15) << 6) + ((((ks << 2) | quad) ^ xm7) << 3));
      #pragma unroll
      for(int c = 0; c < 4; c++)
        bfr[c] = *(const short8*)(sB + ((co + c * 16 + l15) << 6) + ((((ks << 2) | quad) ^ xm7) << 3));
      #pragma unroll
      for(int r = 0; r < 4; r++)
        #pragma unroll
        for(int c = 0; c < 4; c++)
          acc[r][c] = __builtin_amdgcn_mfma_f32_16x16x32_bf16(af[r], bfr[c], acc[r][c], 0, 0, 0);
    }
    __syncthreads();
  }
  // ---- epilogue: stash tile (bf16) into sT[128][132], then rope / v-transpose
  u16* sT = pool;
  #pragma unroll
  for(int r = 0; r < 4; r++)
    #pragma unroll
    for(int c = 0; c < 4; c++){
      int row = ro + r * 16 + quad * 4, col = co + c * 16 + l15;
      #pragma unroll
      for(int j = 0; j < 4; j++) sT[(row + j) * 132 + col] = f2b(acc[r][c][j]);
    }
  __syncthreads();
  int grow0 = mt * 128;
  if(nt < 24){                                  // q or k: rope(+scale) -> qb/kb
    float scale = (nt < 16) ? 0.08838834764831845f : 1.0f;
    u16* dst = (nt < 16) ? qb : kb;
    int dS   = (nt < 16) ? 2048 : 1024;
    int dcol = (nt < 16) ? nt * 128 : (nt - 16) * 128;
    #pragma unroll
    for(int it = 0; it < 16; it++){
      int idx = tid + 256 * it;                 // 4096 u32 pair-words
      int row = idx >> 5, cw = idx & 31;        // h pair = {2cw, 2cw+1}
      int grow = grow0 + row;
      unsigned lo = *(const unsigned*)&sT[row * 132 + 2 * cw];
      unsigned hi = *(const unsigned*)&sT[row * 132 + 64 + 2 * cw];
      float2 sn = *(const float2*)&tab[(grow << 7) + 2 * cw];
      float2 cs = *(const float2*)&tab[(grow << 7) + 64 + 2 * cw];
      float x1a = b2f((u16)lo), x1b = b2f((u16)(lo >> 16));
      float x2a = b2f((u16)hi), x2b = b2f((u16)(hi >> 16));
      float o1a = (x1a * cs.x - x2a * sn.x) * scale;
      float o1b = (x1b * cs.y - x2b * sn.y) * scale;
      float o2a = (x2a * cs.x + x1a * sn.x) * scale;
      float o2b = (x2b * cs.y + x1b * sn.y) * scale;
      unsigned w1 = (unsigned)f2b(o1a) | ((unsigned)f2b(o1b) << 16);
      unsigned w2 = (unsigned)f2b(o2a) | ((unsigned)f2b(o2b) << 16);
      *(unsigned*)&dst[(long)grow * dS + dcol + 2 * cw] = w1;
      *(unsigned*)&dst[(long)grow * dS + dcol + 64 + 2 * cw] = w2;
    }
  } else {                                      // v: transposed -> v_t[b][kv][h][s]
    int b = mt >> 4, kvh = nt - 24;
    u16* vt = vtp + (long)(b * 8 + kvh) * 262144;
    int tcol0 = (mt & 15) * 128;
    int h = tid >> 1, s0 = (tid & 1) * 64;
    #pragma unroll
    for(int i = 0; i < 16; i++){
      int s = s0 + i * 4;
      ushort4 v4 = make_ushort4(sT[(s    ) * 132 + h], sT[(s + 1) * 132 + h],
                                sT[(s + 2) * 132 + h], sT[(s + 3) * 132 + h]);
      *(ushort4*)&vt[(long)h * 2048 + tcol0 + s] = v4;
    }
  }
}

// ---- out projection GEMM: enc[4096x2048] x w_out^T -> fp32 out -------------
__global__ __launch_bounds__(256) void k_gemm_out(
    const u16* __restrict__ A, const u16* __restrict__ Bt0, float* __restrict__ C){
  __shared__ __attribute__((aligned(16))) u16 sA[128 * 64];
  __shared__ __attribute__((aligned(16))) u16 sB[128 * 64];
  int mt = blockIdx.x, nt = blockIdx.y;
  const u16* Bt = Bt0 + (long)nt * 262144;
  int tid = threadIdx.x;
  int lane = tid & 63, wave = tid >> 6, l15 = lane & 15, quad = lane >> 4;
  int ro = (wave & 1) * 64, co = (wave >> 1) * 64;
  int xm7 = l15 & 7;
  int srow = tid >> 3;
  int gch  = (tid & 7) ^ (srow & 7);
  const u16* Ag = A  + ((long)(mt * 128) + srow) * 2048 + (gch << 3);
  const u16* Bg = Bt + (long)srow * 2048 + (gch << 3);
  u16* lA = sA + tid * 8;
  u16* lB = sB + tid * 8;
  floatx4 acc[4][4];
  const floatx4 fz = {0.f, 0.f, 0.f, 0.f};
  #pragma unroll
  for(int r = 0; r < 4; r++)
    #pragma unroll
    for(int c = 0; c < 4; c++) acc[r][c] = fz;
  for(int k0 = 0; k0 < 2048; k0 += 64){
    #pragma unroll
    for(int r = 0; r < 4; r++){
      gload16(Ag + (long)r * 65536 + k0, lA + r * 2048);
      gload16(Bg + (long)r * 65536 + k0, lB + r * 2048);
    }
    __syncthreads();
    #pragma unroll
    for(int ks = 0; ks < 2; ks++){
      short8 af[4], bfr[4];
      #pragma unroll
      for(int r = 0; r < 4; r++)
        af[r]  = *(const short8*)(sA + ((ro + r * 16 + l15) << 6) + ((((ks << 2) | quad) ^ xm7) << 3));
      #pragma unroll
      for(int c = 0; c < 4; c++)
        bfr[c] = *(const short8*)(sB + ((co + c * 16 + l15) << 6) + ((((ks << 2) | quad) ^ xm7) << 3));
      #pragma unroll
      for(int r = 0; r < 4; r++)
        #pragma unroll
        for(int c = 0; c < 4; c++)
          acc[r][c] = __builtin_amdgcn_mfma_f32_16x16x32_bf16(af[r], bfr[c], acc[r][c], 0, 0, 0);
    }
    __syncthreads();
  }
  long rb0 = (long)mt * 128 + ro + quad * 4;
  #pragma unroll
  for(int r = 0; r < 4; r++)
    #pragma unroll
    for(int c = 0; c < 4; c++){
      int col = nt * 128 + co + c * 16 + l15;
      #pragma unroll
      for(int j = 0; j < 4; j++)
        C[(rb0 + r * 16 + j) * 2048 + col] = acc[r][c][j];
    }
}

// ---- flash attention v3.1 --------------------------------------------------
// Q-tile 64 (4 waves x 16 rows), K-tile 64, causal, fixed-max softmax
// (softcap bounds z to [-50,50] so p=e^z is safe). K/V staged by
// global_load_lds into double-buffered XOR-swizzled LDS; one barrier/tile;
// DMA for tile kt+1 flies during compute of tile kt. Diag/non-diag split.
__global__ __launch_bounds__(256) void k_flash(
    const u16* __restrict__ qb, const u16* __restrict__ kb,
    const u16* __restrict__ vt, u16* __restrict__ enc){
  __shared__ __attribute__((aligned(16))) u16 sK[2 * 64 * 128];   // 32 KB
  __shared__ __attribute__((aligned(16))) u16 sVt[2 * 128 * 64];  // 32 KB
  __shared__ __attribute__((aligned(16))) u16 sP[4][16][72];      // 9 KB
  int qt = 31 - blockIdx.y;                    // longest blocks dispatch first
  int hidx = blockIdx.x;
  int b = hidx >> 4, kv = (hidx >> 1) & 7, g = hidx & 1;
  int tid = threadIdx.x;
  int lane = tid & 63, wave = tid >> 6, l15 = lane & 15, quad = lane >> 4;

  short8 qf[4];
  {
    const u16* qg = qb + ((long)b * 2048 + qt * 64 + wave * 16 + l15) * 2048
                       + (kv * 2 + g) * 128 + quad * 8;
    #pragma unroll
    for(int ks = 0; ks < 4; ks++) qf[ks] = *(const short8*)(qg + ks * 32);
  }

  int krow = tid >> 4;
  int kch  = (tid & 15) ^ krow;
  const u16* Kg = kb + ((long)b * 2048 + krow) * 1024 + kv * 128 + (kch << 3);
  int vrow = tid >> 3;
  int vch  = (tid & 7) ^ (vrow & 7);
  const u16* Vg = vt + ((long)(b * 8 + kv) * 128 + vrow) * 2048 + (vch << 3);
  u16* lK = sK  + tid * 8;
  u16* lV = sVt + tid * 8;
  #pragma unroll
  for(int r = 0; r < 4; r++){                   // preload tile 0 -> buf 0
    gload16(Kg + (long)r * 16384, lK + r * 2048);
    gload16(Vg + (long)r * 65536, lV + r * 2048);
  }

  float l_loc[4] = {0.f, 0.f, 0.f, 0.f};
  floatx4 o_acc[8];
  const floatx4 fz = {0.f, 0.f, 0.f, 0.f};
  #pragma unroll
  for(int c = 0; c < 8; c++) o_acc[c] = fz;

  const float c1 = 0.057707801635558536f;      // 2*log2(e)/50
  const float c2 = -144.26950408889634f;       // -100*log2(e)
  const float c3 = 72.13475204444817f;         // 50*log2(e)

  for(int kt = 0; kt <= qt; kt++){
    int buf = (kt & 1) * 8192;
    __syncthreads();                           // drains DMAs for this buf + frees other buf
    if(kt < qt){                               // async stage tile kt+1 into other buf
      int nb = buf ^ 8192;
      #pragma unroll
      for(int r = 0; r < 4; r++){
        gload16(Kg + (long)(kt + 1) * 65536 + (long)r * 16384, lK + nb + r * 2048);
        gload16(Vg + (kt + 1) * 64 + (long)r * 65536, lV + nb + r * 2048);
      }
    }
    // S = Q K^T
    floatx4 s_acc[4];
    #pragma unroll
    for(int c = 0; c < 4; c++) s_acc[c] = fz;
    #pragma unroll
    for(int ks = 0; ks < 4; ks++){
      #pragma unroll
      for(int cb = 0; cb < 4; cb++){
        short8 bk = *(const short8*)(sK + buf + ((cb * 16 + l15) << 7)
                                     + ((((ks << 2) | quad) ^ l15) << 3));
        s_acc[cb] = __builtin_amdgcn_mfma_f32_16x16x32_bf16(qf[ks], bk, s_acc[cb], 0, 0, 0);
      }
    }
    // p = exp(50*tanh(s/50)) = exp2(c2/(u+1) + c3), u = exp2(c1*s)
    if(kt < qt){                               // off-diagonal: no mask
      #pragma unroll
      for(int r = 0; r < 4; r++){
        #pragma unroll
        for(int cb = 0; cb < 4; cb++){
          float s = s_acc[cb][r];
          float u = __builtin_amdgcn_exp2f(c1 * s);
          float d = __builtin_amdgcn_rcpf(u + 1.f);
          float p = __builtin_amdgcn_exp2f(__builtin_fmaf(c2, d, c3));
          l_loc[r] += p;
          sP[wave][quad * 4 + r][cb * 16 + l15] = f2b(p);
        }
      }
    } else {                                   // diagonal tile: causal mask
      int rloc = wave * 16 + quad * 4;
      #pragma unroll
      for(int r = 0; r < 4; r++){
        #pragma unroll
        for(int cb = 0; cb < 4; cb++){
          float s = s_acc[cb][r];
          float u = __builtin_amdgcn_exp2f(c1 * s);
          float d = __builtin_amdgcn_rcpf(u + 1.f);
          float p = __builtin_amdgcn_exp2f(__builtin_fmaf(c2, d, c3));
          if(cb * 16 + l15 > rloc + r) p = 0.f;
          l_loc[r] += p;
          sP[wave][quad * 4 + r][cb * 16 + l15] = f2b(p);
        }
      }
    }
    // O += P V
    #pragma unroll
    for(int ks2 = 0; ks2 < 2; ks2++){
      short8 ap = *(const short8*)&sP[wave][l15][ks2 * 32 + quad * 8];
      #pragma unroll
      for(int c = 0; c < 8; c++){
        short8 bv = *(const short8*)(sVt + buf + ((c * 16 + l15) << 6)
                                     + ((((ks2 << 2) | quad) ^ (l15 & 7)) << 3));
        o_acc[c] = __builtin_amdgcn_mfma_f32_16x16x32_bf16(ap, bv, o_acc[c], 0, 0, 0);
      }
    }
  }
  #pragma unroll
  for(int r = 0; r < 4; r++){
    float l = l_loc[r];
    #pragma unroll
    for(int off = 1; off < 16; off <<= 1) l += __shfl_xor(l, off);
    float invl = 1.f / l;
    long rowe = (long)b * 2048 + qt * 64 + wave * 16 + quad * 4 + r;
    #pragma unroll
    for(int c = 0; c < 8; c++)
      enc[rowe * 2048 + (kv * 2 + g) * 128 + c * 16 + l15] = f2b(o_acc[c][r] * invl);
  }
}

// ---------------------------------------------------------------------------
extern "C" void kernel_launch(void* const* d_in, const int* in_sizes, int n_in,
                              void* d_out, int out_size, void* d_ws, size_t ws_size,
                              hipStream_t stream){
  const float* x     = (const float*)d_in[0];
  const int*   posi  = (const int*)  d_in[1];
  // d_in[2] = attn_mask (causal, known analytically) -- unused
  const float* w_q   = (const float*)d_in[3];
  const float* w_kv  = (const float*)d_in[4];
  const float* w_out = (const float*)d_in[5];
  float* out = (float*)d_out;

  char* w = (char*)d_ws;                        // 74 MB used
  u16* xb     = (u16*)(w);                      // 16 MB (reused as enc after qkv)
  u16* wq_t   = (u16*)(w + 16777216);           //  8 MB [16][128][2048]
  u16* wkv_t  = (u16*)(w + 25165824);           //  8 MB [2][8][128][2048]
  u16* wout_t = (u16*)(w + 33554432);           //  8 MB [2048][2048]
  u16* q_buf  = (u16*)(w + 41943040);           // 16 MB [4096][2048]
  u16* k_buf  = (u16*)(w + 58720256);           //  8 MB [4096][1024]
  u16* v_t    = (u16*)(w + 67108864);           //  8 MB [2][8][128][2048]
  float* tab  = (float*)(w + 75497472);         //  2 MB sin/cos
  u16* enc    = xb;                             // xb dead after qkv

  k_prep    <<<12288, 256, 0, stream>>>(x, xb, w_q, wq_t, w_kv, wkv_t, w_out, wout_t, posi, tab);
  k_gemm_qkv<<<dim3(32, 32), 256, 0, stream>>>(xb, wq_t, wkv_t, tab, q_buf, k_buf, v_t);
  k_flash   <<<dim3(32, 32), 256, 0, stream>>>(q_buf, k_buf, v_t, enc);
  k_gemm_out<<<dim3(32, 16), 256, 0, stream>>>(enc, wout_t, out);
}